// Round 7
// baseline (228.918 us; speedup 1.0000x reference)
//
#include <hip/hip_runtime.h>

// NHWC conv 3x3 stride-1 SAME: x[16,128,128,64] f32, w[3,3,64,128] f32,
// bias[128] f32 -> out[16,128,128,128] f32.
// Implicit GEMM, bf16 MFMA 16x16x32.
// Round 9: R8's wave kept bit-identical in character (B dedup via
// 128px->32co co-quarter waves, [tap][kc][co][ci32] weight layout, 2-deep
// statically-indexed bb[3][2] lookahead, 18 static steps, xor-swizzled LDS,
// same store pattern) but the block now covers HALF a row (64 px x 128 co):
//  - LDS 50.2KB -> 25.3KB  => 6 blocks/CU by LDS
//  - acc 64 -> 32 AGPRs    => ~116 unified regs => 4 waves/SIMD by VGPR
//  => ~16 waves/CU resident (was ~9) with the per-wave latency chain halved.
// Borders via per-chunk predication (no separate zero pass). Grid 4096.

#define HH 128
#define WW 128
#define CIN 64
#define COUT 128

typedef __attribute__((ext_vector_type(8))) short v8s;   // 8 bf16 = 16 B
typedef __attribute__((ext_vector_type(4))) float v4f;   // MFMA C/D

#define ROW_CHUNKS 528             // 66 px * 8 chunks(16B) per px
#define WS_NEEDED  (9u * CIN * COUT * 2u)   // transposed bf16 weights

static __device__ __forceinline__ unsigned short f2bf(float f) {
    unsigned int u = __float_as_uint(f);
    unsigned int r = (u + 0x7fffu + ((u >> 16) & 1u)) >> 16;   // RNE
    return (unsigned short)r;
}

// ---- pre-pass: w[tap][ci][co] fp32 -> wt2[tap][kc][co][ci'] bf16 ----
// ci = kc*32 + ci'; per (tap,kc) a 128co x 32ci' panel, co-major.
__global__ __launch_bounds__(256) void cvt_w(const float* __restrict__ wgt,
                                             unsigned short* __restrict__ wt) {
    int idx = blockIdx.x * 256 + threadIdx.x;   // < 9*64*128 = 73728
    if (idx >= 9 * CIN * COUT) return;
    int co  = idx & (COUT - 1);
    int ci  = (idx >> 7) & (CIN - 1);
    int tap = idx >> 13;
    int kc  = ci >> 5;
    int cl  = ci & 31;
    wt[((tap * 2 + kc) * COUT + co) * 32 + cl] = f2bf(wgt[idx]);
}

// ---- main: half-row implicit-GEMM MFMA conv, high-occupancy ----
__global__ __launch_bounds__(256, 3) void conv_mfma(
    const float* __restrict__ x,            // fp32 [16,128,128,64]
    const unsigned short* __restrict__ wt,  // bf16 [9][2][128][32]
    const float* __restrict__ bias,
    float* __restrict__ out) {
    __shared__ v8s smem[3 * ROW_CHUNKS];    // 25,344 B

    // XCD-aware remap: 4096 blocks, 512 consecutive logicals per XCD
    // (= 2 whole images), so the 3-row halo is L2-local per XCD.
    int bid = blockIdx.x;                   // 0..4095
    int logical = ((bid & 7) << 9) | (bid >> 3);
    int wh = logical & 1;                   // which W half
    int h  = (logical >> 1) & (HH - 1);
    int n  = logical >> 8;
    int w0 = wh << 6;                       // 0 or 64

    int tid  = threadIdx.x;
    int lane = tid & 63;
    int wid  = tid >> 6;           // 0..3 = cout quarter
    int l15  = lane & 15;
    int quad = lane >> 4;

    // ---- stage 3 input rows: fp32 global -> bf16 LDS (swizzled) ----
    // Row covers global px [w0-1, w0+64]; out-of-image chunks -> 0.
    #pragma unroll
    for (int dh = 0; dh < 3; ++dh) {
        int ih = h + dh - 1;
        bool rowok = (ih >= 0) && (ih < HH);       // block-uniform
        const float* rowf = x + ((size_t)(n * HH + (rowok ? ih : 0))) * WW * CIN;
        v8s* dst = smem + dh * ROW_CHUNKS;
        #pragma unroll
        for (int k = 0; k < 3; ++k) {
            int c = tid + (k << 8);                // 0..767, keep < 528
            if (c < ROW_CHUNKS) {
                int lp = c >> 3;                   // local px 0..65
                int gp = w0 - 1 + lp;              // global px -1..128
                v8s ch = (v8s)(short)0;
                if (rowok && gp >= 0 && gp < WW) {
                    const float* p = rowf + gp * CIN + (c & 7) * 8;
                    float4 a = *(const float4*)p;
                    float4 b = *(const float4*)(p + 4);
                    ch[0] = (short)f2bf(a.x); ch[1] = (short)f2bf(a.y);
                    ch[2] = (short)f2bf(a.z); ch[3] = (short)f2bf(a.w);
                    ch[4] = (short)f2bf(b.x); ch[5] = (short)f2bf(b.y);
                    ch[6] = (short)f2bf(b.z); ch[7] = (short)f2bf(b.w);
                }
                dst[c ^ (lp & 7)] = ch;            // xor-swizzle within px
            }
        }
    }

    // per-lane B base: co = wid*32 + tj*16 + l15, ci' slot = quad*8
    const unsigned short* wlane = wt + ((size_t)(wid * 32 + l15)) * 32 + quad * 8;
    // step s: tap = s>>1, kc = s&1 -> panel offset s*128*32 = s*4096
    v8s bb[3][2];                  // 2-step lookahead, statically indexed
    #pragma unroll
    for (int tj = 0; tj < 2; ++tj) {
        bb[0][tj] = *(const v8s*)(wlane + 0 * 4096 + tj * 512);
        bb[1][tj] = *(const v8s*)(wlane + 1 * 4096 + tj * 512);
    }

    __syncthreads();

    v4f acc[4][2];
    #pragma unroll
    for (int i = 0; i < 4; ++i)
        #pragma unroll
        for (int j = 0; j < 2; ++j) acc[i][j] = (v4f)0.f;

    // ---- 18 static steps: tap = s>>1 (dh=tap/3, dw=tap%3), kc = s&1.
    //      B prefetched two steps ahead; afrag staggered one tile ahead. ----
    #pragma unroll
    for (int s = 0; s < 18; ++s) {
        const int tap = s >> 1;
        const int dh  = tap / 3;
        const int dw  = tap % 3;
        const int kc  = s & 1;
        const int cur = s % 3;

        if (s < 16) {                          // issue step s+2's B loads
            const int nb = (s + 2) % 3;
            #pragma unroll
            for (int tj = 0; tj < 2; ++tj)
                bb[nb][tj] = *(const v8s*)(wlane + (s + 2) * 4096 + tj * 512);
        }

        const v8s* srow = smem + dh * ROW_CHUNKS;
        // local px lp = (l15 + ti*16) + dw ; chunk = lp*8 + kc*4 + quad
        const int lp0 = l15 + dw;
        const int sw  = lp0 & 7;               // ti-invariant swizzle key
        const int c0  = lp0 * 8 + kc * 4 + quad;

        v8s a0 = srow[(c0 + 0 * 128) ^ sw];
        v8s a1 = srow[(c0 + 1 * 128) ^ sw];
        #pragma unroll
        for (int tj = 0; tj < 2; ++tj)
            acc[0][tj] = __builtin_amdgcn_mfma_f32_16x16x32_bf16(
                a0, bb[cur][tj], acc[0][tj], 0, 0, 0);
        v8s a2 = srow[(c0 + 2 * 128) ^ sw];
        #pragma unroll
        for (int tj = 0; tj < 2; ++tj)
            acc[1][tj] = __builtin_amdgcn_mfma_f32_16x16x32_bf16(
                a1, bb[cur][tj], acc[1][tj], 0, 0, 0);
        v8s a3 = srow[(c0 + 3 * 128) ^ sw];
        #pragma unroll
        for (int tj = 0; tj < 2; ++tj)
            acc[2][tj] = __builtin_amdgcn_mfma_f32_16x16x32_bf16(
                a2, bb[cur][tj], acc[2][tj], 0, 0, 0);
        #pragma unroll
        for (int tj = 0; tj < 2; ++tj)
            acc[3][tj] = __builtin_amdgcn_mfma_f32_16x16x32_bf16(
                a3, bb[cur][tj], acc[3][tj], 0, 0, 0);
    }

    float bv[2];
    #pragma unroll
    for (int tj = 0; tj < 2; ++tj) bv[tj] = bias[wid * 32 + tj * 16 + l15];

    const float* __restrict__ ob =
        out + ((size_t)(n * HH + h) * WW + w0) * COUT + wid * 32 + l15;
    #pragma unroll
    for (int ti = 0; ti < 4; ++ti) {
        #pragma unroll
        for (int r = 0; r < 4; ++r) {
            int p = ti * 16 + quad * 4 + r;              // C/D: row=quad*4+reg
            float* op = (float*)ob + (size_t)p * COUT;
            op[0]  = acc[ti][0][r] + bv[0];
            op[16] = acc[ti][1][r] + bv[1];
        }
    }
}

// ---- fallback (direct conv) if workspace is too small ----
__global__ __launch_bounds__(256) void conv3x3_direct(
    const float* __restrict__ x, const float* __restrict__ wgt,
    const float* __restrict__ bias, float* __restrict__ out) {
    int idx = blockIdx.x * 256 + threadIdx.x;
    int co = idx & (COUT - 1);
    int w  = (idx >> 7) & (WW - 1);
    int h  = (idx >> 14) & (HH - 1);
    int n  = idx >> 21;
    float acc = bias[co];
    #pragma unroll
    for (int kh = 0; kh < 3; ++kh) {
        int ih = h + kh - 1;
        if (ih < 0 || ih >= HH) continue;
        #pragma unroll
        for (int kw = 0; kw < 3; ++kw) {
            int iw = w + kw - 1;
            if (iw < 0 || iw >= WW) continue;
            const float* xp = x + (((size_t)(n * HH + ih) * WW + iw) * CIN);
            const float* wp = wgt + ((size_t)((kh * 3 + kw) * CIN)) * COUT + co;
            #pragma unroll 8
            for (int ci = 0; ci < CIN; ++ci)
                acc = fmaf(xp[ci], wp[(size_t)ci * COUT], acc);
        }
    }
    out[idx] = acc;
}

extern "C" void kernel_launch(void* const* d_in, const int* in_sizes, int n_in,
                              void* d_out, int out_size, void* d_ws, size_t ws_size,
                              hipStream_t stream) {
    const float* x    = (const float*)d_in[0];
    const float* wgt  = (const float*)d_in[1];
    const float* bias = (const float*)d_in[2];
    float* out = (float*)d_out;

    if (ws_size < (size_t)WS_NEEDED) {
        int blocks = (out_size + 255) / 256;
        conv3x3_direct<<<blocks, 256, 0, stream>>>(x, wgt, bias, out);
        return;
    }

    unsigned short* wt = (unsigned short*)d_ws;
    cvt_w<<<(9 * CIN * COUT + 255) / 256, 256, 0, stream>>>(wgt, wt);
    conv_mfma<<<16 * HH * 2, 256, 0, stream>>>(x, wt, bias, out);
}